// Round 7
// baseline (909.860 us; speedup 1.0000x reference)
//
#include <hip/hip_runtime.h>
#include <hip/hip_cooperative_groups.h>

namespace cg = cooperative_groups;

typedef unsigned int u32;
typedef float vf4 __attribute__((ext_vector_type(4)));

#define NB 2048      // 8 blocks/CU on 256 CUs = 32 waves/CU (HW cap) co-resident
#define NT 256       // threads/block (4 waves)

__device__ __forceinline__ void nt_store4(float4* p, float4 v) {
    __builtin_nontemporal_store(*reinterpret_cast<vf4*>(&v), reinterpret_cast<vf4*>(p));
}
__device__ __forceinline__ float4 nt_load4(const float4* p) {
    vf4 t = __builtin_nontemporal_load(reinterpret_cast<const vf4*>(p));
    float4 r; r.x = t.x; r.y = t.y; r.z = t.z; r.w = t.w;
    return r;
}

__device__ __forceinline__ void mm4(float4 v, float& mn, float& mx) {
    mn = fminf(mn, fminf(fminf(v.x, v.y), fminf(v.z, v.w)));
    mx = fmaxf(mx, fmaxf(fmaxf(v.x, v.y), fmaxf(v.z, v.w)));
}

// block-level min/max reduce; result valid in thread 0 only
__device__ __forceinline__ void block_minmax(float& mn, float& mx,
                                             volatile float* smn, volatile float* smx) {
    #pragma unroll
    for (int off = 32; off > 0; off >>= 1) {
        mn = fminf(mn, __shfl_down(mn, off, 64));
        mx = fmaxf(mx, __shfl_down(mx, off, 64));
    }
    int wave = threadIdx.x >> 6;
    int lane = threadIdx.x & 63;
    if (lane == 0) { smn[wave] = mn; smx[wave] = mx; }
    __syncthreads();
    if (threadIdx.x == 0) {
        #pragma unroll
        for (int w = 1; w < NT / 64; ++w) {
            mn = fminf(mn, smn[w]);
            mx = fmaxf(mx, smx[w]);
        }
    }
}

__device__ __forceinline__ float spline_eval(float xv, float mn, float scale,
                                             const float* sk, const float* sa,
                                             const float* sb, float klo, float khi) {
    float xn = (xv - mn) * scale;
    // initial bin estimate (knots ~ uniform on [0,1]) + boundary correction
    // -> searchsorted(right)-1 semantics
    int b = (int)(xn * 31.0f);
    b = b < 0 ? 0 : (b > 30 ? 30 : b);
    if (xn < sk[b]) {
        b = (b > 0) ? b - 1 : 0;
    } else if (xn >= sk[b + 1]) {
        b = (b < 30) ? b + 1 : 30;
    }
    float val = fmaf(xn - sk[b], sb[b], sa[b]);
    return (xn >= klo && xn <= khi) ? val : 0.0f;
}

__global__ __launch_bounds__(NT, 8) void spline_fused(const float4* __restrict__ x,
                                                      const float* __restrict__ cp,
                                                      const float* __restrict__ knots,
                                                      float* __restrict__ ws,
                                                      float4* __restrict__ out, int n4) {
    __shared__ float sk[32];        // knots
    __shared__ float sa[32];        // control points
    __shared__ float sb[32];        // per-bin slope
    __shared__ float smn[NT / 64], smx[NT / 64];
    __shared__ float sbc[2];        // broadcast of final min/max

    if (threadIdx.x < 32) {
        sk[threadIdx.x] = knots[threadIdx.x];
        sa[threadIdx.x] = cp[threadIdx.x];
    }
    __syncthreads();
    if (threadIdx.x < 31) {
        int i = threadIdx.x;
        sb[i] = (sa[i + 1] - sa[i]) / (sk[i + 1] - sk[i]);
    }
    // sb consumed only after the grid sync below

    const int nb     = gridDim.x;
    const int gtid   = blockIdx.x * NT + threadIdx.x;
    const int stride = nb * NT;

    // ---------- phase 1: min/max, ASCENDING temporal loads, 4-deep ILP ----------
    // (streams x through L2/L3, leaving the tail of x hottest in the 256 MiB L3)
    float mn = INFINITY, mx = -INFINITY;
    int i = gtid;
    for (; i + 3 * stride < n4; i += 4 * stride) {
        float4 a = x[i];
        float4 b = x[i + stride];
        float4 c = x[i + 2 * stride];
        float4 d = x[i + 3 * stride];
        mm4(a, mn, mx); mm4(b, mn, mx); mm4(c, mn, mx); mm4(d, mn, mx);
    }
    for (; i < n4; i += stride) {
        float4 a = x[i];
        mm4(a, mn, mx);
    }
    block_minmax(mn, mx, smn, smx);
    if (threadIdx.x == 0) {
        // agent-scope stores: visible across XCD L2s after the grid barrier
        __hip_atomic_store(&ws[blockIdx.x],      mn, __ATOMIC_RELAXED, __HIP_MEMORY_SCOPE_AGENT);
        __hip_atomic_store(&ws[nb + blockIdx.x], mx, __ATOMIC_RELAXED, __HIP_MEMORY_SCOPE_AGENT);
        __threadfence();
    }

    cg::this_grid().sync();

    // ---------- phase 2: every block redundantly reduces the nb partials ----------
    mn = INFINITY; mx = -INFINITY;
    for (int j = threadIdx.x; j < nb; j += NT) {
        mn = fminf(mn, __hip_atomic_load(&ws[j],      __ATOMIC_RELAXED, __HIP_MEMORY_SCOPE_AGENT));
        mx = fmaxf(mx, __hip_atomic_load(&ws[nb + j], __ATOMIC_RELAXED, __HIP_MEMORY_SCOPE_AGENT));
    }
    block_minmax(mn, mx, smn, smx);
    if (threadIdx.x == 0) { sbc[0] = mn; sbc[1] = mx; }
    __syncthreads();
    mn = sbc[0]; mx = sbc[1];

    const float scale = 1.0f / (mx - mn + 1e-6f);
    const float klo = sk[0], khi = sk[31];

    // ---------- phase 3: apply, BACKWARD traversal (anti-LRU: tail of x is
    // hottest in L3), nt x-loads (single-use) + nt out-stores (must not evict
    // x from the memory-side Infinity Cache). 4-deep ILP. ----------
    const int KMAX = (n4 + stride - 1) / stride;
    int k = KMAX - 1;
    // peel top iterations (bounds-checked) until remaining count is a multiple of 4
    while (k >= 0 && ((k + 1) & 3)) {
        const int idx = k * stride + gtid;
        if (idx < n4) {
            float4 v = nt_load4(&x[idx]);
            float4 r;
            r.x = spline_eval(v.x, mn, scale, sk, sa, sb, klo, khi);
            r.y = spline_eval(v.y, mn, scale, sk, sa, sb, klo, khi);
            r.z = spline_eval(v.z, mn, scale, sk, sa, sb, klo, khi);
            r.w = spline_eval(v.w, mn, scale, sk, sa, sb, klo, khi);
            nt_store4(&out[idx], r);
        }
        --k;
    }
    for (; k >= 3; k -= 4) {
        const int i3 = k * stride + gtid;       // highest index; only the first
        const int i2 = i3 - stride;             // group can have i3 >= n4
        const int i1 = i2 - stride;             // (i2.. always in bounds: see ceil)
        const int i0 = i1 - stride;
        const bool ok3 = (i3 < n4);
        float4 v3 = ok3 ? nt_load4(&x[i3]) : make_float4(0.f, 0.f, 0.f, 0.f);
        float4 v2 = nt_load4(&x[i2]);
        float4 v1 = nt_load4(&x[i1]);
        float4 v0 = nt_load4(&x[i0]);
        float4 r0, r1, r2, r3;
        r3.x = spline_eval(v3.x, mn, scale, sk, sa, sb, klo, khi);
        r3.y = spline_eval(v3.y, mn, scale, sk, sa, sb, klo, khi);
        r3.z = spline_eval(v3.z, mn, scale, sk, sa, sb, klo, khi);
        r3.w = spline_eval(v3.w, mn, scale, sk, sa, sb, klo, khi);
        r2.x = spline_eval(v2.x, mn, scale, sk, sa, sb, klo, khi);
        r2.y = spline_eval(v2.y, mn, scale, sk, sa, sb, klo, khi);
        r2.z = spline_eval(v2.z, mn, scale, sk, sa, sb, klo, khi);
        r2.w = spline_eval(v2.w, mn, scale, sk, sa, sb, klo, khi);
        r1.x = spline_eval(v1.x, mn, scale, sk, sa, sb, klo, khi);
        r1.y = spline_eval(v1.y, mn, scale, sk, sa, sb, klo, khi);
        r1.z = spline_eval(v1.z, mn, scale, sk, sa, sb, klo, khi);
        r1.w = spline_eval(v1.w, mn, scale, sk, sa, sb, klo, khi);
        r0.x = spline_eval(v0.x, mn, scale, sk, sa, sb, klo, khi);
        r0.y = spline_eval(v0.y, mn, scale, sk, sa, sb, klo, khi);
        r0.z = spline_eval(v0.z, mn, scale, sk, sa, sb, klo, khi);
        r0.w = spline_eval(v0.w, mn, scale, sk, sa, sb, klo, khi);
        if (ok3) nt_store4(&out[i3], r3);
        nt_store4(&out[i2], r2);
        nt_store4(&out[i1], r1);
        nt_store4(&out[i0], r0);
    }
}

// ======================= fallback path (round-5 split, verified 510 µs) =======================

__device__ __forceinline__ u32 f2ord(float f) {
    u32 b = __float_as_uint(f);
    return (b & 0x80000000u) ? ~b : (b | 0x80000000u);
}
__device__ __forceinline__ float ord2f(u32 k) {
    u32 b = (k & 0x80000000u) ? (k ^ 0x80000000u) : ~k;
    return __uint_as_float(b);
}

__global__ __launch_bounds__(256) void minmax_kernel(const float4* __restrict__ x, int n4,
                                                     u32* __restrict__ ws) {
    float mn = INFINITY, mx = -INFINITY;
    int stride = gridDim.x * blockDim.x;
    for (int i = blockIdx.x * blockDim.x + threadIdx.x; i < n4; i += stride) {
        float4 v = x[i];
        mm4(v, mn, mx);
    }
    #pragma unroll
    for (int off = 32; off > 0; off >>= 1) {
        mn = fminf(mn, __shfl_down(mn, off, 64));
        mx = fmaxf(mx, __shfl_down(mx, off, 64));
    }
    __shared__ float smn[4], smx[4];
    int wave = threadIdx.x >> 6;
    int lane = threadIdx.x & 63;
    if (lane == 0) { smn[wave] = mn; smx[wave] = mx; }
    __syncthreads();
    if (threadIdx.x == 0) {
        #pragma unroll
        for (int w = 1; w < 4; ++w) { mn = fminf(mn, smn[w]); mx = fmaxf(mx, smx[w]); }
        atomicMax(&ws[0], ~f2ord(mn));   // min via inverted key; cell inits to 0
        atomicMax(&ws[1],  f2ord(mx));
    }
}

__global__ __launch_bounds__(256) void apply_kernel(const float4* __restrict__ x,
                                                    const float* __restrict__ cp,
                                                    const float* __restrict__ knots,
                                                    const u32* __restrict__ ws,
                                                    float4* __restrict__ out, int n4) {
    __shared__ float sk[32];
    __shared__ float sa[32];
    __shared__ float sb[32];
    if (threadIdx.x < 32) {
        sk[threadIdx.x] = knots[threadIdx.x];
        sa[threadIdx.x] = cp[threadIdx.x];
    }
    __syncthreads();
    if (threadIdx.x < 31) {
        int i = threadIdx.x;
        sb[i] = (sa[i + 1] - sa[i]) / (sk[i + 1] - sk[i]);
    }
    __syncthreads();

    float mn = ord2f(~ws[0]);
    float mx = ord2f(ws[1]);
    float scale = 1.0f / (mx - mn + 1e-6f);
    float klo = sk[0], khi = sk[31];

    const int gtid   = blockIdx.x * blockDim.x + threadIdx.x;
    const int stride = gridDim.x * blockDim.x;
    const int KMAX   = (n4 + stride - 1) / stride;

    for (int k = KMAX - 1; k >= 0; --k) {
        const int i = k * stride + gtid;
        if (i >= n4) continue;
        float4 v = nt_load4(&x[i]);
        float4 r;
        r.x = spline_eval(v.x, mn, scale, sk, sa, sb, klo, khi);
        r.y = spline_eval(v.y, mn, scale, sk, sa, sb, klo, khi);
        r.z = spline_eval(v.z, mn, scale, sk, sa, sb, klo, khi);
        r.w = spline_eval(v.w, mn, scale, sk, sa, sb, klo, khi);
        nt_store4(&out[i], r);
    }
}

extern "C" void kernel_launch(void* const* d_in, const int* in_sizes, int n_in,
                              void* d_out, int out_size, void* d_ws, size_t ws_size,
                              hipStream_t stream) {
    const float4* x     = (const float4*)d_in[0];
    const float*  cp    = (const float*)d_in[1];
    const float*  knots = (const float*)d_in[2];
    float4* out = (float4*)d_out;

    int n  = in_sizes[0];      // 64 * 1048576, divisible by 4
    int n4 = n / 4;

    bool fused_ok = (ws_size >= (size_t)(2 * NB) * sizeof(float));
    if (fused_ok) {
        float* ws = (float*)d_ws;
        void* args[] = {(void*)&x, (void*)&cp, (void*)&knots, (void*)&ws, (void*)&out, (void*)&n4};
        hipError_t e = hipLaunchCooperativeKernel((const void*)spline_fused,
                                                  dim3(NB), dim3(NT), args, 0, stream);
        if (e == hipSuccess) return;
        // else fall through to the verified split path
    }

    u32* ws32 = (u32*)d_ws;
    hipMemsetAsync(ws32, 0x00, 8, stream);
    minmax_kernel<<<4096, 256, 0, stream>>>(x, n4, ws32);
    apply_kernel <<<8192, 256, 0, stream>>>(x, cp, knots, ws32, out, n4);
}

// Round 8
// 511.838 us; speedup vs baseline: 1.7776x; 1.7776x over previous
//
#include <hip/hip_runtime.h>

typedef unsigned int u32;
typedef float vf4 __attribute__((ext_vector_type(4)));

__device__ __forceinline__ void nt_store4(float4* p, float4 v) {
    __builtin_nontemporal_store(*reinterpret_cast<vf4*>(&v), reinterpret_cast<vf4*>(p));
}
__device__ __forceinline__ float4 nt_load4(const float4* p) {
    vf4 t = __builtin_nontemporal_load(reinterpret_cast<const vf4*>(p));
    float4 r; r.x = t.x; r.y = t.y; r.z = t.z; r.w = t.w;
    return r;
}

__device__ __forceinline__ void mm4(float4 v, float& mn, float& mx) {
    mn = fminf(mn, fminf(fminf(v.x, v.y), fminf(v.z, v.w)));
    mx = fmaxf(mx, fmaxf(fmaxf(v.x, v.y), fmaxf(v.z, v.w)));
}

// Order-preserving float<->uint mapping so we can use integer atomic max.
// min is tracked as max over the INVERTED key, so both cells init to 0
// (single 8-byte memset).
__device__ __forceinline__ u32 f2ord(float f) {
    u32 b = __float_as_uint(f);
    return (b & 0x80000000u) ? ~b : (b | 0x80000000u);
}
__device__ __forceinline__ float ord2f(u32 k) {
    u32 b = (k & 0x80000000u) ? (k ^ 0x80000000u) : ~k;
    return __uint_as_float(b);
}

// ---------------- Kernel A: global min/max reduction ----------------
// Regular (temporal) loads on purpose: streams x ascending through L2/L3,
// leaving x resident in the 256 MiB Infinity Cache (x is exactly 256 MB).
// 2-deep ILP: more loads in flight while the fills' dirty L3 lines drain.
__global__ __launch_bounds__(256) void minmax_kernel(const float4* __restrict__ x, int n4,
                                                     u32* __restrict__ ws) {
    float mn = INFINITY, mx = -INFINITY;
    int stride = gridDim.x * blockDim.x;
    int i = blockIdx.x * blockDim.x + threadIdx.x;
    for (; i + stride < n4; i += 2 * stride) {
        float4 a = x[i];
        float4 b = x[i + stride];
        mm4(a, mn, mx);
        mm4(b, mn, mx);
    }
    for (; i < n4; i += stride) {
        float4 a = x[i];
        mm4(a, mn, mx);
    }
    // wave(64) shuffle reduction
    #pragma unroll
    for (int off = 32; off > 0; off >>= 1) {
        mn = fminf(mn, __shfl_down(mn, off, 64));
        mx = fmaxf(mx, __shfl_down(mx, off, 64));
    }
    __shared__ float smn[4], smx[4];
    int wave = threadIdx.x >> 6;
    int lane = threadIdx.x & 63;
    if (lane == 0) { smn[wave] = mn; smx[wave] = mx; }
    __syncthreads();
    if (threadIdx.x == 0) {
        #pragma unroll
        for (int w = 1; w < 4; ++w) { mn = fminf(mn, smn[w]); mx = fmaxf(mx, smx[w]); }
        atomicMax(&ws[0], ~f2ord(mn));   // min via inverted key; cell inits to 0
        atomicMax(&ws[1],  f2ord(mx));   // max;                  cell inits to 0
    }
}

// ---------------- Kernel B: spline apply ----------------
// Traverses x BACKWARD (anti-LRU: tail of x is most recently cached in L3
// after kernel A). x-loads and out-stores are NONTEMPORAL: x is single-use
// here, and the out stream must not evict x from the memory-side L3.
// 2-deep ILP on the load/store streams.
__global__ __launch_bounds__(256) void apply_kernel(const float4* __restrict__ x,
                                                    const float* __restrict__ cp,
                                                    const float* __restrict__ knots,
                                                    const u32* __restrict__ ws,
                                                    float4* __restrict__ out, int n4) {
    __shared__ float sk[32];   // knots
    __shared__ float sa[32];   // control points (intercepts)
    __shared__ float sb[32];   // per-bin slope (cp[i+1]-cp[i])/(k[i+1]-k[i])
    if (threadIdx.x < 32) {
        sk[threadIdx.x] = knots[threadIdx.x];
        sa[threadIdx.x] = cp[threadIdx.x];
    }
    __syncthreads();
    if (threadIdx.x < 31) {
        int i = threadIdx.x;
        sb[i] = (sa[i + 1] - sa[i]) / (sk[i + 1] - sk[i]);
    }
    __syncthreads();

    float mn = ord2f(~ws[0]);
    float mx = ord2f(ws[1]);
    float scale = 1.0f / (mx - mn + 1e-6f);
    float klo = sk[0], khi = sk[31];

    const int gtid   = blockIdx.x * blockDim.x + threadIdx.x;
    const int stride = gridDim.x * blockDim.x;
    const int KMAX   = (n4 + stride - 1) / stride;

    int k = KMAX - 1;
    for (; k >= 1; k -= 2) {
        const int i1 = k * stride + gtid;        // higher index; only the first
        const int i0 = i1 - stride;              // group can be OOB. i0 always in.
        const bool ok1 = (i1 < n4);
        float4 v1 = ok1 ? nt_load4(&x[i1]) : make_float4(0.f, 0.f, 0.f, 0.f);
        float4 v0 = nt_load4(&x[i0]);
        float4 r0, r1;
        float* v1p = (float*)&v1; float* r1p = (float*)&r1;
        float* v0p = (float*)&v0; float* r0p = (float*)&r0;
        #pragma unroll
        for (int c = 0; c < 4; ++c) {
            float xn = (v1p[c] - mn) * scale;
            int b = (int)(xn * 31.0f);
            b = b < 0 ? 0 : (b > 30 ? 30 : b);
            if (xn < sk[b])            b = (b > 0) ? b - 1 : 0;
            else if (xn >= sk[b + 1])  b = (b < 30) ? b + 1 : 30;
            float val = fmaf(xn - sk[b], sb[b], sa[b]);
            r1p[c] = (xn >= klo && xn <= khi) ? val : 0.0f;
        }
        #pragma unroll
        for (int c = 0; c < 4; ++c) {
            float xn = (v0p[c] - mn) * scale;
            int b = (int)(xn * 31.0f);
            b = b < 0 ? 0 : (b > 30 ? 30 : b);
            if (xn < sk[b])            b = (b > 0) ? b - 1 : 0;
            else if (xn >= sk[b + 1])  b = (b < 30) ? b + 1 : 30;
            float val = fmaf(xn - sk[b], sb[b], sa[b]);
            r0p[c] = (xn >= klo && xn <= khi) ? val : 0.0f;
        }
        if (ok1) nt_store4(&out[i1], r1);
        nt_store4(&out[i0], r0);
    }
    if (k == 0) {
        const int i = gtid;
        if (i < n4) {
            float4 v = nt_load4(&x[i]);
            float4 r;
            float* vp = (float*)&v; float* rp = (float*)&r;
            #pragma unroll
            for (int c = 0; c < 4; ++c) {
                float xn = (vp[c] - mn) * scale;
                int b = (int)(xn * 31.0f);
                b = b < 0 ? 0 : (b > 30 ? 30 : b);
                if (xn < sk[b])            b = (b > 0) ? b - 1 : 0;
                else if (xn >= sk[b + 1])  b = (b < 30) ? b + 1 : 30;
                float val = fmaf(xn - sk[b], sb[b], sa[b]);
                rp[c] = (xn >= klo && xn <= khi) ? val : 0.0f;
            }
            nt_store4(&out[i], r);
        }
    }
}

extern "C" void kernel_launch(void* const* d_in, const int* in_sizes, int n_in,
                              void* d_out, int out_size, void* d_ws, size_t ws_size,
                              hipStream_t stream) {
    const float* x     = (const float*)d_in[0];
    const float* cp    = (const float*)d_in[1];
    const float* knots = (const float*)d_in[2];
    float* out = (float*)d_out;
    u32* ws = (u32*)d_ws;

    int n  = in_sizes[0];      // 64 * 1048576, divisible by 4
    int n4 = n / 4;

    // both reduction cells (inverted-min key, max key) initialize to 0
    hipMemsetAsync(ws, 0x00, 8, stream);

    minmax_kernel<<<4096, 256, 0, stream>>>((const float4*)x, n4, ws);
    apply_kernel <<<8192, 256, 0, stream>>>((const float4*)x, cp, knots, ws,
                                            (float4*)out, n4);
}